// Round 12
// baseline (1131.503 us; speedup 1.0000x reference)
//
#include <hip/hip_runtime.h>

typedef unsigned int uint;
typedef unsigned short ushort;
typedef short bf16x8 __attribute__((ext_vector_type(8)));
typedef ushort ushort4v __attribute__((ext_vector_type(4)));
typedef float f32x4 __attribute__((ext_vector_type(4)));

#define HD 1024
#define BT 2048
#define NEXP 6
#define MAXR 4096
#define GT 16   // tokens per gating block
#define NG 128  // BN partial-sum groups
#define RG 16   // rows per group (NG*RG == BT)

typedef __attribute__((address_space(1))) void as1_void;
typedef __attribute__((address_space(3))) void as3_void;
#define ASYNC16(g, l) \
  __builtin_amdgcn_global_load_lds((as1_void*)(const void*)(g), (as3_void*)(void*)(l), 16, 0, 0)

// ---------------- bf16 split helpers ----------------
__device__ static inline ushort f32_to_bf16(float f) {
  uint u = __float_as_uint(f);
  u = (u + 0x7fffu + ((u >> 16) & 1u)) >> 16;
  return (ushort)u;
}
__device__ static inline float bf16_to_f32(ushort h) {
  return __uint_as_float(((uint)h) << 16);
}
__device__ static inline void split2(float f, ushort* hi, ushort* lo) {
  ushort h = f32_to_bf16(f);
  *hi = h;
  *lo = f32_to_bf16(f - bf16_to_f32(h));
}

// ---------------- Threefry-2x32 (matches JAX) ----------------
__host__ __device__ static inline unsigned rotl32(unsigned v, int n) {
  return (v << n) | (v >> (32 - n));
}
__host__ __device__ static inline void tf2x32(unsigned k0, unsigned k1,
                                              unsigned x0, unsigned x1,
                                              unsigned* o0, unsigned* o1) {
  unsigned ks0 = k0, ks1 = k1, ks2 = k0 ^ k1 ^ 0x1BD11BDAu;
  x0 += ks0; x1 += ks1;
  const int ra[4] = {13, 15, 26, 6};
  const int rb[4] = {17, 29, 16, 24};
  #pragma unroll
  for (int r = 0; r < 4; ++r) { x0 += x1; x1 = rotl32(x1, ra[r]); x1 ^= x0; }
  x0 += ks1; x1 += ks2 + 1u;
  #pragma unroll
  for (int r = 0; r < 4; ++r) { x0 += x1; x1 = rotl32(x1, rb[r]); x1 ^= x0; }
  x0 += ks2; x1 += ks0 + 2u;
  #pragma unroll
  for (int r = 0; r < 4; ++r) { x0 += x1; x1 = rotl32(x1, ra[r]); x1 ^= x0; }
  x0 += ks0; x1 += ks1 + 3u;
  #pragma unroll
  for (int r = 0; r < 4; ++r) { x0 += x1; x1 = rotl32(x1, rb[r]); x1 ^= x0; }
  x0 += ks1; x1 += ks2 + 4u;
  #pragma unroll
  for (int r = 0; r < 4; ++r) { x0 += x1; x1 = rotl32(x1, ra[r]); x1 ^= x0; }
  x0 += ks2; x1 += ks0 + 5u;
  *o0 = x0; *o1 = x1;
}

// ---------------- init ----------------
__global__ void init_ws_k(int* cnt, float* loss) {
  int t = threadIdx.x;
  if (t < 32) cnt[t] = 0;
  if (t == 32) loss[0] = 0.0f;
}

// ---------------- weight transpose + split: W(K x N) -> Th,Tl (N x K bf16) ----------------
__global__ __launch_bounds__(256) void transpose_split_k(
    const float* __restrict__ W, ushort* __restrict__ Th, ushort* __restrict__ Tl,
    int K, int N) {
  size_t boff = (size_t)blockIdx.z * K * N;
  W += boff; Th += boff; Tl += boff;
  __shared__ float T[32][33];
  int n0 = blockIdx.x * 32, k0 = blockIdx.y * 32;
  int tid = threadIdx.x;
  int r = tid >> 3, c4 = (tid & 7) * 4;
  float4 v = *(const float4*)&W[(size_t)(k0 + r) * N + n0 + c4];
  T[c4 + 0][r] = v.x; T[c4 + 1][r] = v.y; T[c4 + 2][r] = v.z; T[c4 + 3][r] = v.w;
  __syncthreads();
  ushort4v hh, ll;
  #pragma unroll
  for (int j = 0; j < 4; ++j) {
    float f = T[r][c4 + j];
    ushort h, l; split2(f, &h, &l);
    hh[j] = h; ll[j] = l;
  }
  size_t o = (size_t)(n0 + r) * K + k0 + c4;
  *(ushort4v*)&Th[o] = hh;
  *(ushort4v*)&Tl[o] = ll;
}

// ---------------- elementwise split (for input x) ----------------
__global__ __launch_bounds__(256) void split_plain_k(
    const float* __restrict__ X, ushort* __restrict__ Xh, ushort* __restrict__ Xl) {
  size_t i = ((size_t)blockIdx.x * 256 + threadIdx.x) * 4;
  float4 v = *(const float4*)&X[i];
  ushort4v hh, ll;
  float f[4] = {v.x, v.y, v.z, v.w};
  #pragma unroll
  for (int j = 0; j < 4; ++j) { ushort h, l; split2(f[j], &h, &l); hh[j] = h; ll[j] = l; }
  *(ushort4v*)&Xh[i] = hh;
  *(ushort4v*)&Xl[i] = ll;
}

// ---------------- MFMA GEMM, async-staged, swizzled LDS, split-K ----------------
// 128x64 tile, 512 threads / 8 waves (each wave a 32x32 sub-tile, acc[2][2]).
// TRIPLE-buffered LDS (72 KB => 2 blocks/CU) with prefetch distance 2 and
// COUNTED vmcnt (T4): per k-step the wait is vmcnt(loads-of-next-tile), so
// tile t+1's loads stay in flight across the barrier and tile t's loads get
// TWO compute phases of flight time instead of one.
// Sync sequence per step (hazard-audited):
//   s_waitcnt vmcnt(N)  -> own loads for tile t landed (N = next tile's loads)
//   s_barrier           -> all waves' loads for tile t landed (each waited own)
//   sched_barrier(0)    -> pins following ds_reads/STAGE after the barrier
//                          (rule #18 — the R0 race was ds_reads hoisting here)
//   STAGE(tile t+2)     -> WAR-safe: writes buf((t-1)%3); its readers (iter
//                          t-1) drained ds_reads before reaching this barrier
//   ds_read buf(t%3); MFMA
// Per-output-element accumulation order identical to previous versions.
// MODE 0: C_partial[z] = A @ B^T slice-of-K (no bias, raw f32 partial)
// MODE 2: expert: gather A rows via list, full K, relu, scatter C rows; z = expert
template <int MODE>
__global__ __launch_bounds__(512, 4) void gemm_mfma_k(
    const ushort* __restrict__ Ah, const ushort* __restrict__ Al,
    const ushort* __restrict__ Bh, const ushort* __restrict__ Bl,
    float* __restrict__ P,
    const int* __restrict__ cnt, const int* __restrict__ list,
    int N, int K, int ksteps) {
  int bz = blockIdx.z;
  int row0 = blockIdx.y * 128, col0 = blockIdx.x * 64;
  int nrows = 0, kbase = 0;
  if (MODE == 2) {
    size_t wo = (size_t)bz * N * K;
    Bh += wo; Bl += wo;
    nrows = cnt[bz];
    list += bz * MAXR;
    if (row0 >= nrows) return;
  } else {
    P += (size_t)bz * BT * N;
    kbase = bz * ksteps * 32;
  }
  __shared__ ushort sAh[3][4096], sAl[3][4096], sBh[3][2048], sBl[3][2048];
  int tid = threadIdx.x;
  int lane = tid & 63, w = tid >> 6;
  // wave -> 32x32 output sub-tile: 4 row groups x 2 col groups
  int wm = (w & 3) * 32;
  int wn = (w >> 2) * 32;  // w in 0..7 -> wn 0 or 32

  // A staging: one 16B chunk per thread (512 chunks); slot XOR-swizzled by row
  const ushort *pAh, *pAl, *pBh = Bh, *pBl = Bl;
  {
    int r = tid >> 2;
    int cl = (tid & 3) ^ ((r ^ (r >> 2)) & 3);
    int ra = row0 + r;
    if (MODE == 2) ra = (ra < nrows) ? (list[ra] & (BT - 1)) : 0;
    size_t ao = (size_t)ra * K + kbase + cl * 8;
    pAh = Ah + ao; pAl = Al + ao;
  }
  // B staging: 256 chunks, waves 0-3 only
  if (tid < 256) {
    int r = tid >> 2;
    int cl = (tid & 3) ^ ((r ^ (r >> 2)) & 3);
    size_t bo = (size_t)(col0 + r) * K + kbase + cl * 8;
    pBh = Bh + bo; pBl = Bl + bo;
  }
  int lb = w * 512;  // ushort offset, wave-uniform; lane spreads by 16B in HW

  // fragment LDS offsets (swizzled to match staging)
  int fr = lane & 15, cq = lane >> 4;
  int offA[2], offB[2];
  #pragma unroll
  for (int i = 0; i < 2; ++i) {
    int rA = wm + i * 16 + fr;
    offA[i] = rA * 32 + (cq ^ ((rA ^ (rA >> 2)) & 3)) * 8;
    int rB = wn + i * 16 + fr;
    offB[i] = rB * 32 + (cq ^ ((rB ^ (rB >> 2)) & 3)) * 8;
  }

  f32x4 acc[2][2] = {};

#define STAGE(buf, ko)                       \
  do {                                       \
    ASYNC16(pAh + (ko), sAh[buf] + lb);      \
    ASYNC16(pAl + (ko), sAl[buf] + lb);      \
    if (w < 4) {                             \
      ASYNC16(pBh + (ko), sBh[buf] + lb);    \
      ASYNC16(pBl + (ko), sBl[buf] + lb);    \
    }                                        \
  } while (0)

  // prologue: two tiles in flight
  STAGE(0, 0);
  if (ksteps > 1) STAGE(1, 32);

  int cur = 0;
  for (int ks = 0; ks < ksteps; ++ks) {
    // wait for tile ks (leave tile ks+1's loads in flight if it exists)
    if (ks + 1 < ksteps) {
      if (w < 4) asm volatile("s_waitcnt vmcnt(4)" ::: "memory");
      else       asm volatile("s_waitcnt vmcnt(2)" ::: "memory");
    } else {
      asm volatile("s_waitcnt vmcnt(0)" ::: "memory");
    }
    __builtin_amdgcn_s_barrier();
    __builtin_amdgcn_sched_barrier(0);

    // prefetch tile ks+2 into buffer (cur+2)%3 (WAR-safe: see header comment)
    if (ks + 2 < ksteps) {
      int nb = cur + 2; if (nb >= 3) nb -= 3;
      STAGE(nb, (ks + 2) * 32);
    }

    bf16x8 ah[2], al[2], bh[2], bl[2];
    #pragma unroll
    for (int i = 0; i < 2; ++i) {
      ah[i] = *(const bf16x8*)&sAh[cur][offA[i]];
      al[i] = *(const bf16x8*)&sAl[cur][offA[i]];
      bh[i] = *(const bf16x8*)&sBh[cur][offB[i]];
      bl[i] = *(const bf16x8*)&sBl[cur][offB[i]];
    }
    __builtin_amdgcn_s_setprio(1);
    #pragma unroll
    for (int mi = 0; mi < 2; ++mi)
      #pragma unroll
      for (int ni = 0; ni < 2; ++ni) {
        acc[mi][ni] = __builtin_amdgcn_mfma_f32_16x16x32_bf16(ah[mi], bh[ni], acc[mi][ni], 0, 0, 0);
        acc[mi][ni] = __builtin_amdgcn_mfma_f32_16x16x32_bf16(ah[mi], bl[ni], acc[mi][ni], 0, 0, 0);
        acc[mi][ni] = __builtin_amdgcn_mfma_f32_16x16x32_bf16(al[mi], bh[ni], acc[mi][ni], 0, 0, 0);
      }
    __builtin_amdgcn_s_setprio(0);
    cur += 1; if (cur >= 3) cur = 0;
  }
#undef STAGE

  // epilogue: C/D layout col = lane&15, row = (lane>>4)*4 + reg
  if (MODE == 2) {
    #pragma unroll
    for (int mi = 0; mi < 2; ++mi) {
      int rb = row0 + wm + mi * 16 + cq * 4;
      #pragma unroll
      for (int r = 0; r < 4; ++r) {
        int row = rb + r;
        if (row < nrows) {
          size_t dro = (size_t)list[row] * N;
          #pragma unroll
          for (int ni = 0; ni < 2; ++ni)
            P[dro + col0 + wn + ni * 16 + fr] = fmaxf(acc[mi][ni][r], 0.0f);
        }
      }
    }
  } else {
    #pragma unroll
    for (int mi = 0; mi < 2; ++mi) {
      int rb = row0 + wm + mi * 16 + cq * 4;
      #pragma unroll
      for (int r = 0; r < 4; ++r) {
        size_t ro = (size_t)(rb + r) * N;
        #pragma unroll
        for (int ni = 0; ni < 2; ++ni)
          P[ro + col0 + wn + ni * 16 + fr] = acc[mi][ni][r];
      }
    }
  }
}

// ---------------- split-K reduce + bias -> xl f32, + BN column partial sums ----------------
template <int NS>
__global__ __launch_bounds__(256) void reduce_dense_k(
    const float* __restrict__ P, const float* __restrict__ bias,
    float* __restrict__ xl, float* __restrict__ psum) {
  int c = blockIdx.x * 256 + threadIdx.x;
  int r0 = blockIdx.y * RG;
  float bv = bias[c];
  float s = 0.0f;
  for (int r = r0; r < r0 + RG; ++r) {
    float v = bv;
    #pragma unroll
    for (int j = 0; j < NS; ++j) v += P[(size_t)j * BT * HD + (size_t)r * HD + c];
    xl[(size_t)r * HD + c] = v;
    s += v;
  }
  psum[blockIdx.y * HD + c] = s;
}

// ---------------- split-K reduce + bias -> xl f32 + bf16 hi/lo (MoE input) ----------------
template <int NS>
__global__ __launch_bounds__(256) void reduce_split_k(
    const float* __restrict__ P, const float* __restrict__ bias,
    float* __restrict__ xl, ushort* __restrict__ Xh, ushort* __restrict__ Xl2) {
  int c = blockIdx.x * 256 + threadIdx.x;
  int r0 = blockIdx.y * RG;
  float bv = bias[c];
  for (int r = r0; r < r0 + RG; ++r) {
    float v = bv;
    #pragma unroll
    for (int j = 0; j < NS; ++j) v += P[(size_t)j * BT * HD + (size_t)r * HD + c];
    xl[(size_t)r * HD + c] = v;
    ushort h, l; split2(v, &h, &l);
    Xh[(size_t)r * HD + c] = h;
    Xl2[(size_t)r * HD + c] = l;
  }
}

// ---------------- output reduce: out = sum P + bias ----------------
__global__ __launch_bounds__(256) void reduce_out_k(
    const float* __restrict__ P, const float* __restrict__ bias,
    float* __restrict__ out) {
  int c = threadIdx.x;
  int r0 = blockIdx.y * RG;
  float bv = bias[c];
  for (int r = r0; r < r0 + RG; ++r) {
    float v = bv;
    #pragma unroll
    for (int j = 0; j < 8; ++j) v += P[(size_t)j * BT * 256 + (size_t)r * 256 + c];
    out[(size_t)r * 256 + c] = v;
  }
}

// ---------------- gating: 16 tokens per 256-thread block ----------------
__global__ __launch_bounds__(256) void gating_k(
    const float* __restrict__ xl, const float* __restrict__ wg,
    int* __restrict__ cnt, int* __restrict__ toklist,
    float* __restrict__ g1o, float* __restrict__ g2o,
    float* __restrict__ loss, unsigned key0, unsigned key1) {
  int tid = threadIdx.x;
  int lane = tid & 63, wv = tid >> 6;
  int q = lane >> 4, ql = lane & 15;
  int t = wv * 4 + q;                 // token slot 0..15 within block
  int b = blockIdx.x * GT + t;        // global token id

  const float* row = xl + (size_t)b * HD;
  float p[NEXP] = {0, 0, 0, 0, 0, 0};
  for (int d = ql; d < HD; d += 16) {
    float xv = row[d];
    const float* w = wg + (size_t)d * NEXP;
    #pragma unroll
    for (int e = 0; e < NEXP; ++e) p[e] += xv * w[e];
  }
  #pragma unroll
  for (int off = 8; off > 0; off >>= 1)
    #pragma unroll
    for (int e = 0; e < NEXP; ++e) p[e] += __shfl_xor(p[e], off);

  __shared__ int   li1[GT], li2[GT];
  __shared__ float lg1[GT], lg2[GT], lgg1[GT];
  __shared__ int   base_s[NEXP];

  if (ql == 0) {
    float mx = p[0];
    #pragma unroll
    for (int e = 1; e < NEXP; ++e) mx = fmaxf(mx, p[e]);
    float ex[NEXP], s = 0.0f;
    #pragma unroll
    for (int e = 0; e < NEXP; ++e) { ex[e] = expf(p[e] - mx); s += ex[e]; }
    float raw[NEXP];
    #pragma unroll
    for (int e = 0; e < NEXP; ++e) raw[e] = ex[e] / s;
    int i1 = 0; float gg1 = raw[0];
    #pragma unroll
    for (int e = 1; e < NEXP; ++e) if (raw[e] > gg1) { gg1 = raw[e]; i1 = e; }
    int i2 = -1; float gg2 = -1.0f;
    #pragma unroll
    for (int e = 0; e < NEXP; ++e) {
      float v = (e == i1) ? 0.0f : raw[e];
      if (v > gg2) { gg2 = v; i2 = e; }
    }
    float den = gg1 + gg2 + 1e-9f;
    float g1n = gg1 / den;
    float g2n = gg2 / den;
    unsigned o0, o1;
    tf2x32(key0, key1, 0u, (unsigned)b, &o0, &o1);
    unsigned bits = o0 ^ o1;
    float prob = __uint_as_float((bits >> 9) | 0x3f800000u) - 1.0f;
    int keep = prob < (g2n / 0.2f);
    li1[t] = i1;
    li2[t] = keep ? i2 : -1;
    lg1[t] = g1n;
    lg2[t] = keep ? g2n : 0.0f;
    lgg1[t] = gg1;
  }
  __syncthreads();

  if (tid < NEXP) {
    int c = 0;
    for (int j = 0; j < GT; ++j) c += (li1[j] == tid) + (li2[j] == tid);
    base_s[tid] = (c > 0) ? atomicAdd(&cnt[tid], c) : 0;
  }
  if (tid == 64) {  // loss partial: one atomic per block
    float s = 0.0f;
    for (int j = 0; j < GT; ++j) s += lgg1[j];
    atomicAdd(loss, s);
  }
  __syncthreads();

  if (tid < GT) {
    int tt = tid;
    int i1 = li1[tt], i2 = li2[tt];
    int bb = blockIdx.x * GT + tt;
    g1o[bb] = lg1[tt];
    g2o[bb] = lg2[tt];
    int o1 = 0, o2 = 0;
    for (int j = 0; j < tt; ++j) {
      o1 += (li1[j] == i1) + (li2[j] == i1);
      o2 += (li1[j] == i2) + (li2[j] == i2);
    }
    toklist[i1 * MAXR + base_s[i1] + o1] = bb;
    if (i2 >= 0) toklist[i2 * MAXR + base_s[i2] + o2] = BT + bb;
  }
}

// ---------------- combine + column partial sums ----------------
__global__ __launch_bounds__(256) void combine_sum_k(
    const float* __restrict__ xl, const float* __restrict__ eo,
    const float* __restrict__ g1o, const float* __restrict__ g2o,
    float* __restrict__ y, float* __restrict__ psum) {
  int c = blockIdx.x * 256 + threadIdx.x;
  int r0 = blockIdx.y * RG;
  float s = 0.0f;
  for (int r = r0; r < r0 + RG; ++r) {
    float v = xl[(size_t)r * HD + c];
    float w1g = g1o[r];
    v += w1g * eo[(size_t)r * HD + c];
    float w2g = g2o[r];
    if (w2g != 0.0f) v += w2g * eo[(size_t)(r + BT) * HD + c];
    y[(size_t)r * HD + c] = v;
    s += v;
  }
  psum[blockIdx.y * HD + c] = s;
}

// ---------------- fold psum -> mu (tiny) ----------------
__global__ __launch_bounds__(256) void fold_mu_k(
    const float* __restrict__ psum, float* __restrict__ mu) {
  int c = blockIdx.x * 256 + threadIdx.x;
  float s = 0.0f;
  for (int i = 0; i < NG; ++i) s += psum[i * HD + c];
  mu[c] = s * (1.0f / 2048.0f);
}

// ---------------- fold psumsq -> inv (tiny) ----------------
__global__ __launch_bounds__(256) void fold_inv_k(
    const float* __restrict__ psumsq, float* __restrict__ inv) {
  int c = blockIdx.x * 256 + threadIdx.x;
  float ss = 0.0f;
  for (int i = 0; i < NG; ++i) ss += psumsq[i * HD + c];
  float var = ss * (1.0f / 2048.0f);
  inv[c] = 1.0f / sqrtf(var + 1e-5f);
}

__global__ __launch_bounds__(256) void var_partial_k(
    const float* __restrict__ src, const float* __restrict__ mu_,
    float* __restrict__ psumsq) {
  int c = blockIdx.x * 256 + threadIdx.x;
  float mu = mu_[c];
  int r0 = blockIdx.y * RG;
  float ss = 0.0f;
  for (int r = r0; r < r0 + RG; ++r) {
    float d = src[(size_t)r * HD + c] - mu;
    ss += d * d;
  }
  psumsq[blockIdx.y * HD + c] = ss;
}

// ---------------- BN apply + relu -> bf16 hi/lo split ----------------
__global__ __launch_bounds__(256) void bn_split_k(
    const float* __restrict__ src, const float* __restrict__ mu_,
    const float* __restrict__ inv_, const float* __restrict__ gamma,
    const float* __restrict__ beta, ushort* __restrict__ Hh,
    ushort* __restrict__ Hl) {
  int c = blockIdx.x * 256 + threadIdx.x;
  float mu = mu_[c];
  float inv = inv_[c];
  float ga = gamma[c], be = beta[c];
  int r0 = blockIdx.y * RG;
  for (int r = r0; r < r0 + RG; ++r) {
    float v = src[(size_t)r * HD + c];
    float o = fmaxf(ga * (v - mu) * inv + be, 0.0f);
    ushort h, l; split2(o, &h, &l);
    Hh[(size_t)r * HD + c] = h;
    Hl[(size_t)r * HD + c] = l;
  }
}

// ---------------- loss finalize ----------------
__global__ void finalize_loss_k(const float* __restrict__ loss, float* __restrict__ out) {
  if (threadIdx.x == 0) out[BT * 256] = loss[0] * (0.01f * 36.0f / 12288.0f);
}

extern "C" void kernel_launch(void* const* d_in, const int* in_sizes, int n_in,
                              void* d_out, int out_size, void* d_ws, size_t ws_size,
                              hipStream_t stream) {
  const float* x     = (const float*)d_in[0];
  const float* in_W  = (const float*)d_in[1];
  const float* in_b  = (const float*)d_in[2];
  const float* in_g  = (const float*)d_in[3];
  const float* in_be = (const float*)d_in[4];
  const float* sp_W  = (const float*)d_in[5];
  const float* sp_b  = (const float*)d_in[6];
  const float* sp_g  = (const float*)d_in[7];
  const float* sp_be = (const float*)d_in[8];
  const float* sp_gate = (const float*)d_in[9];
  const float* sp_w1 = (const float*)d_in[10];
  const float* dn_W  = (const float*)d_in[11];
  const float* dn_b  = (const float*)d_in[12];
  const float* dn_g  = (const float*)d_in[13];
  const float* dn_be = (const float*)d_in[14];
  const float* out_W = (const float*)d_in[15];
  const float* out_b = (const float*)d_in[16];
  float* out = (float*)d_out;

  // ---- workspace layout ----
  char* base = (char*)d_ws;
  size_t off = 0;
  auto alloc = [&](size_t bytes) { void* p = base + off; off = (off + bytes + 255) & ~(size_t)255; return p; };
  float*  xl     = (float*)alloc((size_t)BT * HD * 4);          // 8 MB
  float*  P      = (float*)alloc((size_t)4 * BT * HD * 4);      // 32 MB; eo = P[0:16MB], y = P+4M floats
  float*  eo     = P;                                           // 4096 x 1024 f32 (alias)
  float*  y      = P + (size_t)4 * 1024 * 1024;                 // 2048 x 1024 f32 (alias)
  float*  psum   = (float*)alloc(NG * HD * 4);
  float*  psumsq = (float*)alloc(NG * HD * 4);
  float*  muv    = (float*)alloc(HD * 4);
  float*  invv   = (float*)alloc(HD * 4);
  float*  g1o    = (float*)alloc(BT * 4);
  float*  g2o    = (float*)alloc(BT * 4);
  float*  loss   = (float*)alloc(256);
  int*    cnt    = (int*)alloc(256);
  int*    toklist= (int*)alloc(NEXP * MAXR * 4);
  ushort* Hh     = (ushort*)alloc((size_t)BT * HD * 2);
  ushort* Hl     = (ushort*)alloc((size_t)BT * HD * 2);
  ushort* XLh    = (ushort*)alloc((size_t)BT * HD * 2);
  ushort* XLl    = (ushort*)alloc((size_t)BT * HD * 2);
  ushort* inWTh  = (ushort*)alloc((size_t)2048 * HD * 2);
  ushort* inWTl  = (ushort*)alloc((size_t)2048 * HD * 2);
  ushort* spWTh  = (ushort*)alloc((size_t)4 * HD * HD * 2);
  ushort* spWTl  = (ushort*)alloc((size_t)4 * HD * HD * 2);
  ushort* dnWTh  = (ushort*)alloc((size_t)4 * HD * HD * 2);
  ushort* dnWTl  = (ushort*)alloc((size_t)4 * HD * HD * 2);
  ushort* outWTh = (ushort*)alloc((size_t)HD * 256 * 2);
  ushort* outWTl = (ushort*)alloc((size_t)HD * 256 * 2);
  // w1 transpose region; Xh/Xl for input x alias its head (dead after input GEMM,
  // and transpose of w1 is launched after the input GEMM in stream order).
  ushort* w1Th   = (ushort*)alloc((size_t)24 * HD * HD * 2);    // 48 MB
  ushort* w1Tl   = (ushort*)alloc((size_t)24 * HD * HD * 2);    // 48 MB
  ushort* Xh     = w1Th;                                        // 2048x2048 bf16 (8 MB)
  ushort* Xl     = w1Th + (size_t)BT * 2048;                    // next 8 MB

  unsigned lk0[4], lk1[4];
  for (int i = 0; i < 4; ++i) tf2x32(0u, 42u, 0u, (unsigned)i, &lk0[i], &lk1[i]);

  dim3 blk(256);
  dim3 gblk(512);
  init_ws_k<<<1, 64, 0, stream>>>(cnt, loss);

  // ---- weight prep (w1 deferred until after input GEMM) ----
  transpose_split_k<<<dim3(32, 64, 1), blk, 0, stream>>>(in_W, inWTh, inWTl, 2048, HD);
  transpose_split_k<<<dim3(32, 32, 4), blk, 0, stream>>>(sp_W, spWTh, spWTl, HD, HD);
  transpose_split_k<<<dim3(32, 32, 4), blk, 0, stream>>>(dn_W, dnWTh, dnWTl, HD, HD);
  transpose_split_k<<<dim3(8, 32, 1), blk, 0, stream>>>(out_W, outWTh, outWTl, HD, 256);
  split_plain_k<<<(BT * 2048) / 1024, blk, 0, stream>>>(x, Xh, Xl);

  // ---- input layer: split-K=4 GEMM, fused reduce+bias+colsum, BN ----
  gemm_mfma_k<0><<<dim3(16, 16, 4), gblk, 0, stream>>>(Xh, Xl, inWTh, inWTl, P,
                                                       nullptr, nullptr, HD, 2048, 16);
  reduce_dense_k<4><<<dim3(4, NG), blk, 0, stream>>>(P, in_b, xl, psum);
  // w1 transpose now (Xh/Xl dead)
  transpose_split_k<<<dim3(32, 32, 24), blk, 0, stream>>>(sp_w1, w1Th, w1Tl, HD, HD);
  fold_mu_k<<<4, blk, 0, stream>>>(psum, muv);
  var_partial_k<<<dim3(4, NG), blk, 0, stream>>>(xl, muv, psumsq);
  fold_inv_k<<<4, blk, 0, stream>>>(psumsq, invv);
  bn_split_k<<<dim3(4, NG), blk, 0, stream>>>(xl, muv, invv, in_g, in_be, Hh, Hl);

  // ---- sparse MoE layers ----
  for (int i = 0; i < 4; ++i) {
    gemm_mfma_k<0><<<dim3(16, 16, 4), gblk, 0, stream>>>(Hh, Hl, spWTh + (size_t)i * HD * HD,
                                                         spWTl + (size_t)i * HD * HD, P,
                                                         nullptr, nullptr, HD, HD, 8);
    reduce_split_k<4><<<dim3(4, NG), blk, 0, stream>>>(P, sp_b + i * HD, xl, XLh, XLl);
    gating_k<<<BT / GT, blk, 0, stream>>>(xl, sp_gate + (size_t)i * HD * NEXP,
                                          cnt + i * 8, toklist, g1o, g2o, loss, lk0[i], lk1[i]);
    gemm_mfma_k<2><<<dim3(16, 32, NEXP), gblk, 0, stream>>>(XLh, XLl,
                                                            w1Th + (size_t)i * NEXP * HD * HD,
                                                            w1Tl + (size_t)i * NEXP * HD * HD,
                                                            eo, cnt + i * 8, toklist, HD, HD, 32);
    combine_sum_k<<<dim3(4, NG), blk, 0, stream>>>(xl, eo, g1o, g2o, y, psum);
    fold_mu_k<<<4, blk, 0, stream>>>(psum, muv);
    var_partial_k<<<dim3(4, NG), blk, 0, stream>>>(y, muv, psumsq);
    fold_inv_k<<<4, blk, 0, stream>>>(psumsq, invv);
    bn_split_k<<<dim3(4, NG), blk, 0, stream>>>(y, muv, invv, sp_g + i * HD,
                                                sp_be + i * HD, Hh, Hl);
  }

  // ---- dense layers ----
  for (int i = 0; i < 4; ++i) {
    gemm_mfma_k<0><<<dim3(16, 16, 4), gblk, 0, stream>>>(Hh, Hl, dnWTh + (size_t)i * HD * HD,
                                                         dnWTl + (size_t)i * HD * HD, P,
                                                         nullptr, nullptr, HD, HD, 8);
    reduce_dense_k<4><<<dim3(4, NG), blk, 0, stream>>>(P, dn_b + i * HD, xl, psum);
    fold_mu_k<<<4, blk, 0, stream>>>(psum, muv);
    var_partial_k<<<dim3(4, NG), blk, 0, stream>>>(xl, muv, psumsq);
    fold_inv_k<<<4, blk, 0, stream>>>(psumsq, invv);
    bn_split_k<<<dim3(4, NG), blk, 0, stream>>>(xl, muv, invv, dn_g + i * HD,
                                                dn_be + i * HD, Hh, Hl);
  }

  // ---- output projection: split-K=8 ----
  gemm_mfma_k<0><<<dim3(4, 16, 8), gblk, 0, stream>>>(Hh, Hl, outWTh, outWTl, P,
                                                      nullptr, nullptr, 256, HD, 4);
  reduce_out_k<<<dim3(1, NG), blk, 0, stream>>>(P, out_b, out);
  finalize_loss_k<<<1, 64, 0, stream>>>(loss, out);
}

// Round 13
// 1115.109 us; speedup vs baseline: 1.0147x; 1.0147x over previous
//
#include <hip/hip_runtime.h>

typedef unsigned int uint;
typedef unsigned short ushort;
typedef short bf16x8 __attribute__((ext_vector_type(8)));
typedef ushort ushort4v __attribute__((ext_vector_type(4)));
typedef float f32x4 __attribute__((ext_vector_type(4)));

#define HD 1024
#define BT 2048
#define NEXP 6
#define MAXR 4096
#define GT 16   // tokens per gating block
#define NG 128  // BN partial-sum groups
#define RG 16   // rows per group (NG*RG == BT)

typedef __attribute__((address_space(1))) void as1_void;
typedef __attribute__((address_space(3))) void as3_void;
#define ASYNC16(g, l) \
  __builtin_amdgcn_global_load_lds((as1_void*)(const void*)(g), (as3_void*)(void*)(l), 16, 0, 0)

// ---------------- bf16 split helpers ----------------
__device__ static inline ushort f32_to_bf16(float f) {
  uint u = __float_as_uint(f);
  u = (u + 0x7fffu + ((u >> 16) & 1u)) >> 16;
  return (ushort)u;
}
__device__ static inline float bf16_to_f32(ushort h) {
  return __uint_as_float(((uint)h) << 16);
}
__device__ static inline void split2(float f, ushort* hi, ushort* lo) {
  ushort h = f32_to_bf16(f);
  *hi = h;
  *lo = f32_to_bf16(f - bf16_to_f32(h));
}

// ---------------- Threefry-2x32 (matches JAX) ----------------
__host__ __device__ static inline unsigned rotl32(unsigned v, int n) {
  return (v << n) | (v >> (32 - n));
}
__host__ __device__ static inline void tf2x32(unsigned k0, unsigned k1,
                                              unsigned x0, unsigned x1,
                                              unsigned* o0, unsigned* o1) {
  unsigned ks0 = k0, ks1 = k1, ks2 = k0 ^ k1 ^ 0x1BD11BDAu;
  x0 += ks0; x1 += ks1;
  const int ra[4] = {13, 15, 26, 6};
  const int rb[4] = {17, 29, 16, 24};
  #pragma unroll
  for (int r = 0; r < 4; ++r) { x0 += x1; x1 = rotl32(x1, ra[r]); x1 ^= x0; }
  x0 += ks1; x1 += ks2 + 1u;
  #pragma unroll
  for (int r = 0; r < 4; ++r) { x0 += x1; x1 = rotl32(x1, rb[r]); x1 ^= x0; }
  x0 += ks2; x1 += ks0 + 2u;
  #pragma unroll
  for (int r = 0; r < 4; ++r) { x0 += x1; x1 = rotl32(x1, ra[r]); x1 ^= x0; }
  x0 += ks0; x1 += ks1 + 3u;
  #pragma unroll
  for (int r = 0; r < 4; ++r) { x0 += x1; x1 = rotl32(x1, rb[r]); x1 ^= x0; }
  x0 += ks1; x1 += ks2 + 4u;
  #pragma unroll
  for (int r = 0; r < 4; ++r) { x0 += x1; x1 = rotl32(x1, ra[r]); x1 ^= x0; }
  x0 += ks2; x1 += ks0 + 5u;
  *o0 = x0; *o1 = x1;
}

// ---------------- init ----------------
__global__ void init_ws_k(int* cnt, float* loss) {
  int t = threadIdx.x;
  if (t < 32) cnt[t] = 0;
  if (t == 32) loss[0] = 0.0f;
}

// ---------------- weight transpose + split: W(K x N) -> Th,Tl (N x K bf16) ----------------
__global__ __launch_bounds__(256) void transpose_split_k(
    const float* __restrict__ W, ushort* __restrict__ Th, ushort* __restrict__ Tl,
    int K, int N) {
  size_t boff = (size_t)blockIdx.z * K * N;
  W += boff; Th += boff; Tl += boff;
  __shared__ float T[32][33];
  int n0 = blockIdx.x * 32, k0 = blockIdx.y * 32;
  int tid = threadIdx.x;
  int r = tid >> 3, c4 = (tid & 7) * 4;
  float4 v = *(const float4*)&W[(size_t)(k0 + r) * N + n0 + c4];
  T[c4 + 0][r] = v.x; T[c4 + 1][r] = v.y; T[c4 + 2][r] = v.z; T[c4 + 3][r] = v.w;
  __syncthreads();
  ushort4v hh, ll;
  #pragma unroll
  for (int j = 0; j < 4; ++j) {
    float f = T[r][c4 + j];
    ushort h, l; split2(f, &h, &l);
    hh[j] = h; ll[j] = l;
  }
  size_t o = (size_t)(n0 + r) * K + k0 + c4;
  *(ushort4v*)&Th[o] = hh;
  *(ushort4v*)&Tl[o] = ll;
}

// ---------------- elementwise split (for input x) ----------------
__global__ __launch_bounds__(256) void split_plain_k(
    const float* __restrict__ X, ushort* __restrict__ Xh, ushort* __restrict__ Xl) {
  size_t i = ((size_t)blockIdx.x * 256 + threadIdx.x) * 4;
  float4 v = *(const float4*)&X[i];
  ushort4v hh, ll;
  float f[4] = {v.x, v.y, v.z, v.w};
  #pragma unroll
  for (int j = 0; j < 4; ++j) { ushort h, l; split2(f[j], &h, &l); hh[j] = h; ll[j] = l; }
  *(ushort4v*)&Xh[i] = hh;
  *(ushort4v*)&Xl[i] = ll;
}

// ---------------- MFMA GEMM, async-staged, swizzled LDS, split-K ----------------
// R5 structure (measured best per-dispatch): 128x128 tile, 512 threads/8 waves
// (each wave a 32x64 sub-tile, acc[2][4]), 64 KB double-buffered LDS (2
// blocks/CU), prefetch-first + one __syncthreads per k-step.
// NEW: bijective XCD-aware block swizzle (T1). Counters showed FETCH_SIZE ~= the
// zero-reuse worst case (61 MB vs 17 MB unique): consecutive blocks round-robin
// across the 8 XCDs, so every XCD refetches the same A/B panels through the
// fabric (~1.2 TB/s effective = the dispatch time). Remap so each XCD gets a
// contiguous x-fastest chunk -> per-XCD working set ~2-4 MB (L2-fits), fabric
// traffic ~16-20 MB. vbid = (bid%8)*(nwg/8) + bid/8; all grids are %8==0 so
// this is bijective. Pure relabeling -> results bit-identical.
// MODE 0: C_partial[z] = A @ B^T slice-of-K (no bias, raw f32 partial)
// MODE 2: expert: gather A rows via list, full K, relu, scatter C rows; z = expert
template <int MODE>
__global__ __launch_bounds__(512, 4) void gemm_mfma_k(
    const ushort* __restrict__ Ah, const ushort* __restrict__ Al,
    const ushort* __restrict__ Bh, const ushort* __restrict__ Bl,
    float* __restrict__ P,
    const int* __restrict__ cnt, const int* __restrict__ list,
    int N, int K, int ksteps) {
  // ---- XCD-aware bijective swizzle ----
  int nbx = gridDim.x, nby = gridDim.y;
  int nwg = nbx * nby * gridDim.z;
  int bid = blockIdx.x + nbx * (blockIdx.y + nby * blockIdx.z);
  int q = nwg >> 3;  // grids are multiples of 8
  int vbid = (bid & 7) * q + (bid >> 3);
  int bx = vbid % nbx;
  int t2 = vbid / nbx;
  int by = t2 % nby;
  int bz = t2 / nby;

  int row0 = by * 128, col0 = bx * 128;
  int nrows = 0, kbase = 0;
  if (MODE == 2) {
    size_t wo = (size_t)bz * N * K;
    Bh += wo; Bl += wo;
    nrows = cnt[bz];
    list += bz * MAXR;
    if (row0 >= nrows) return;
  } else {
    P += (size_t)bz * BT * N;
    kbase = bz * ksteps * 32;
  }
  __shared__ ushort sAh[2][4096], sAl[2][4096], sBh[2][4096], sBl[2][4096];
  int tid = threadIdx.x;
  int lane = tid & 63, w = tid >> 6;
  // wave -> 32x64 output sub-tile: 4 row groups x 2 col groups
  int wm = (w & 3) * 32, wn = (w >> 2) * 64;

  // staging: one 16B chunk per array per thread; chunk slot XOR-swizzled by row
  const ushort *pAh, *pAl, *pBh, *pBl;
  {
    int r = tid >> 2;
    int cl = (tid & 3) ^ ((r ^ (r >> 2)) & 3);
    int ra = row0 + r;
    if (MODE == 2) ra = (ra < nrows) ? (list[ra] & (BT - 1)) : 0;
    size_t ao = (size_t)ra * K + kbase + cl * 8;
    size_t bo = (size_t)(col0 + r) * K + kbase + cl * 8;
    pAh = Ah + ao; pAl = Al + ao;
    pBh = Bh + bo; pBl = Bl + bo;
  }
  int lb = w * 512;  // ushort offset, wave-uniform; lane spreads by 16B in HW

  // fragment LDS offsets (swizzled to match staging)
  int fr = lane & 15, cq = lane >> 4;
  int offA[2], offB[4];
  #pragma unroll
  for (int i = 0; i < 2; ++i) {
    int rA = wm + i * 16 + fr;
    offA[i] = rA * 32 + (cq ^ ((rA ^ (rA >> 2)) & 3)) * 8;
  }
  #pragma unroll
  for (int i = 0; i < 4; ++i) {
    int rB = wn + i * 16 + fr;
    offB[i] = rB * 32 + (cq ^ ((rB ^ (rB >> 2)) & 3)) * 8;
  }

  f32x4 acc[2][4] = {};

#define STAGE(buf, ko)                    \
  do {                                    \
    ASYNC16(pAh + (ko), sAh[buf] + lb);   \
    ASYNC16(pAl + (ko), sAl[buf] + lb);   \
    ASYNC16(pBh + (ko), sBh[buf] + lb);   \
    ASYNC16(pBl + (ko), sBl[buf] + lb);   \
  } while (0)

  // prologue: fill buffer 0
  STAGE(0, 0);
  __syncthreads();

  int cur = 0;
  for (int ks = 0; ks < ksteps; ++ks) {
    // issue prefetch of next k-step into the other buffer FIRST,
    // so HBM/L2/L3 latency hides under this step's ds_read + MFMA
    if (ks + 1 < ksteps) STAGE(cur ^ 1, (ks + 1) * 32);

    bf16x8 ah[2], al[2], bh[4], bl[4];
    #pragma unroll
    for (int i = 0; i < 2; ++i) {
      ah[i] = *(const bf16x8*)&sAh[cur][offA[i]];
      al[i] = *(const bf16x8*)&sAl[cur][offA[i]];
    }
    #pragma unroll
    for (int i = 0; i < 4; ++i) {
      bh[i] = *(const bf16x8*)&sBh[cur][offB[i]];
      bl[i] = *(const bf16x8*)&sBl[cur][offB[i]];
    }
    __builtin_amdgcn_s_setprio(1);
    #pragma unroll
    for (int mi = 0; mi < 2; ++mi)
      #pragma unroll
      for (int ni = 0; ni < 4; ++ni) {
        acc[mi][ni] = __builtin_amdgcn_mfma_f32_16x16x32_bf16(ah[mi], bh[ni], acc[mi][ni], 0, 0, 0);
        acc[mi][ni] = __builtin_amdgcn_mfma_f32_16x16x32_bf16(ah[mi], bl[ni], acc[mi][ni], 0, 0, 0);
        acc[mi][ni] = __builtin_amdgcn_mfma_f32_16x16x32_bf16(al[mi], bh[ni], acc[mi][ni], 0, 0, 0);
      }
    __builtin_amdgcn_s_setprio(0);
    __syncthreads();  // drains this step's prefetch (vmcnt 0) + fences LDS
    cur ^= 1;
  }
#undef STAGE

  // epilogue: C/D layout col = lane&15, row = (lane>>4)*4 + reg
  if (MODE == 2) {
    #pragma unroll
    for (int mi = 0; mi < 2; ++mi) {
      int rb = row0 + wm + mi * 16 + cq * 4;
      #pragma unroll
      for (int r = 0; r < 4; ++r) {
        int row = rb + r;
        if (row < nrows) {
          size_t dro = (size_t)list[row] * N;
          #pragma unroll
          for (int ni = 0; ni < 4; ++ni)
            P[dro + col0 + wn + ni * 16 + fr] = fmaxf(acc[mi][ni][r], 0.0f);
        }
      }
    }
  } else {
    #pragma unroll
    for (int mi = 0; mi < 2; ++mi) {
      int rb = row0 + wm + mi * 16 + cq * 4;
      #pragma unroll
      for (int r = 0; r < 4; ++r) {
        size_t ro = (size_t)(rb + r) * N;
        #pragma unroll
        for (int ni = 0; ni < 4; ++ni)
          P[ro + col0 + wn + ni * 16 + fr] = acc[mi][ni][r];
      }
    }
  }
}

// ---------------- split-K reduce + bias -> xl f32, + BN column partial sums ----------------
template <int NS>
__global__ __launch_bounds__(256) void reduce_dense_k(
    const float* __restrict__ P, const float* __restrict__ bias,
    float* __restrict__ xl, float* __restrict__ psum) {
  int c = blockIdx.x * 256 + threadIdx.x;
  int r0 = blockIdx.y * RG;
  float bv = bias[c];
  float s = 0.0f;
  for (int r = r0; r < r0 + RG; ++r) {
    float v = bv;
    #pragma unroll
    for (int j = 0; j < NS; ++j) v += P[(size_t)j * BT * HD + (size_t)r * HD + c];
    xl[(size_t)r * HD + c] = v;
    s += v;
  }
  psum[blockIdx.y * HD + c] = s;
}

// ---------------- split-K reduce + bias -> xl f32 + bf16 hi/lo (MoE input) ----------------
template <int NS>
__global__ __launch_bounds__(256) void reduce_split_k(
    const float* __restrict__ P, const float* __restrict__ bias,
    float* __restrict__ xl, ushort* __restrict__ Xh, ushort* __restrict__ Xl2) {
  int c = blockIdx.x * 256 + threadIdx.x;
  int r0 = blockIdx.y * RG;
  float bv = bias[c];
  for (int r = r0; r < r0 + RG; ++r) {
    float v = bv;
    #pragma unroll
    for (int j = 0; j < NS; ++j) v += P[(size_t)j * BT * HD + (size_t)r * HD + c];
    xl[(size_t)r * HD + c] = v;
    ushort h, l; split2(v, &h, &l);
    Xh[(size_t)r * HD + c] = h;
    Xl2[(size_t)r * HD + c] = l;
  }
}

// ---------------- output reduce: out = sum P + bias ----------------
__global__ __launch_bounds__(256) void reduce_out_k(
    const float* __restrict__ P, const float* __restrict__ bias,
    float* __restrict__ out) {
  int c = threadIdx.x;
  int r0 = blockIdx.y * RG;
  float bv = bias[c];
  for (int r = r0; r < r0 + RG; ++r) {
    float v = bv;
    #pragma unroll
    for (int j = 0; j < 8; ++j) v += P[(size_t)j * BT * 256 + (size_t)r * 256 + c];
    out[(size_t)r * 256 + c] = v;
  }
}

// ---------------- gating: 16 tokens per 256-thread block ----------------
__global__ __launch_bounds__(256) void gating_k(
    const float* __restrict__ xl, const float* __restrict__ wg,
    int* __restrict__ cnt, int* __restrict__ toklist,
    float* __restrict__ g1o, float* __restrict__ g2o,
    float* __restrict__ loss, unsigned key0, unsigned key1) {
  int tid = threadIdx.x;
  int lane = tid & 63, wv = tid >> 6;
  int q = lane >> 4, ql = lane & 15;
  int t = wv * 4 + q;                 // token slot 0..15 within block
  int b = blockIdx.x * GT + t;        // global token id

  const float* row = xl + (size_t)b * HD;
  float p[NEXP] = {0, 0, 0, 0, 0, 0};
  for (int d = ql; d < HD; d += 16) {
    float xv = row[d];
    const float* w = wg + (size_t)d * NEXP;
    #pragma unroll
    for (int e = 0; e < NEXP; ++e) p[e] += xv * w[e];
  }
  #pragma unroll
  for (int off = 8; off > 0; off >>= 1)
    #pragma unroll
    for (int e = 0; e < NEXP; ++e) p[e] += __shfl_xor(p[e], off);

  __shared__ int   li1[GT], li2[GT];
  __shared__ float lg1[GT], lg2[GT], lgg1[GT];
  __shared__ int   base_s[NEXP];

  if (ql == 0) {
    float mx = p[0];
    #pragma unroll
    for (int e = 1; e < NEXP; ++e) mx = fmaxf(mx, p[e]);
    float ex[NEXP], s = 0.0f;
    #pragma unroll
    for (int e = 0; e < NEXP; ++e) { ex[e] = expf(p[e] - mx); s += ex[e]; }
    float raw[NEXP];
    #pragma unroll
    for (int e = 0; e < NEXP; ++e) raw[e] = ex[e] / s;
    int i1 = 0; float gg1 = raw[0];
    #pragma unroll
    for (int e = 1; e < NEXP; ++e) if (raw[e] > gg1) { gg1 = raw[e]; i1 = e; }
    int i2 = -1; float gg2 = -1.0f;
    #pragma unroll
    for (int e = 0; e < NEXP; ++e) {
      float v = (e == i1) ? 0.0f : raw[e];
      if (v > gg2) { gg2 = v; i2 = e; }
    }
    float den = gg1 + gg2 + 1e-9f;
    float g1n = gg1 / den;
    float g2n = gg2 / den;
    unsigned o0, o1;
    tf2x32(key0, key1, 0u, (unsigned)b, &o0, &o1);
    unsigned bits = o0 ^ o1;
    float prob = __uint_as_float((bits >> 9) | 0x3f800000u) - 1.0f;
    int keep = prob < (g2n / 0.2f);
    li1[t] = i1;
    li2[t] = keep ? i2 : -1;
    lg1[t] = g1n;
    lg2[t] = keep ? g2n : 0.0f;
    lgg1[t] = gg1;
  }
  __syncthreads();

  if (tid < NEXP) {
    int c = 0;
    for (int j = 0; j < GT; ++j) c += (li1[j] == tid) + (li2[j] == tid);
    base_s[tid] = (c > 0) ? atomicAdd(&cnt[tid], c) : 0;
  }
  if (tid == 64) {  // loss partial: one atomic per block
    float s = 0.0f;
    for (int j = 0; j < GT; ++j) s += lgg1[j];
    atomicAdd(loss, s);
  }
  __syncthreads();

  if (tid < GT) {
    int tt = tid;
    int i1 = li1[tt], i2 = li2[tt];
    int bb = blockIdx.x * GT + tt;
    g1o[bb] = lg1[tt];
    g2o[bb] = lg2[tt];
    int o1 = 0, o2 = 0;
    for (int j = 0; j < tt; ++j) {
      o1 += (li1[j] == i1) + (li2[j] == i1);
      o2 += (li1[j] == i2) + (li2[j] == i2);
    }
    toklist[i1 * MAXR + base_s[i1] + o1] = bb;
    if (i2 >= 0) toklist[i2 * MAXR + base_s[i2] + o2] = BT + bb;
  }
}

// ---------------- combine + column partial sums ----------------
__global__ __launch_bounds__(256) void combine_sum_k(
    const float* __restrict__ xl, const float* __restrict__ eo,
    const float* __restrict__ g1o, const float* __restrict__ g2o,
    float* __restrict__ y, float* __restrict__ psum) {
  int c = blockIdx.x * 256 + threadIdx.x;
  int r0 = blockIdx.y * RG;
  float s = 0.0f;
  for (int r = r0; r < r0 + RG; ++r) {
    float v = xl[(size_t)r * HD + c];
    float w1g = g1o[r];
    v += w1g * eo[(size_t)r * HD + c];
    float w2g = g2o[r];
    if (w2g != 0.0f) v += w2g * eo[(size_t)(r + BT) * HD + c];
    y[(size_t)r * HD + c] = v;
    s += v;
  }
  psum[blockIdx.y * HD + c] = s;
}

// ---------------- fold psum -> mu (tiny) ----------------
__global__ __launch_bounds__(256) void fold_mu_k(
    const float* __restrict__ psum, float* __restrict__ mu) {
  int c = blockIdx.x * 256 + threadIdx.x;
  float s = 0.0f;
  for (int i = 0; i < NG; ++i) s += psum[i * HD + c];
  mu[c] = s * (1.0f / 2048.0f);
}

// ---------------- fold psumsq -> inv (tiny) ----------------
__global__ __launch_bounds__(256) void fold_inv_k(
    const float* __restrict__ psumsq, float* __restrict__ inv) {
  int c = blockIdx.x * 256 + threadIdx.x;
  float ss = 0.0f;
  for (int i = 0; i < NG; ++i) ss += psumsq[i * HD + c];
  float var = ss * (1.0f / 2048.0f);
  inv[c] = 1.0f / sqrtf(var + 1e-5f);
}

__global__ __launch_bounds__(256) void var_partial_k(
    const float* __restrict__ src, const float* __restrict__ mu_,
    float* __restrict__ psumsq) {
  int c = blockIdx.x * 256 + threadIdx.x;
  float mu = mu_[c];
  int r0 = blockIdx.y * RG;
  float ss = 0.0f;
  for (int r = r0; r < r0 + RG; ++r) {
    float d = src[(size_t)r * HD + c] - mu;
    ss += d * d;
  }
  psumsq[blockIdx.y * HD + c] = ss;
}

// ---------------- BN apply + relu -> bf16 hi/lo split ----------------
__global__ __launch_bounds__(256) void bn_split_k(
    const float* __restrict__ src, const float* __restrict__ mu_,
    const float* __restrict__ inv_, const float* __restrict__ gamma,
    const float* __restrict__ beta, ushort* __restrict__ Hh,
    ushort* __restrict__ Hl) {
  int c = blockIdx.x * 256 + threadIdx.x;
  float mu = mu_[c];
  float inv = inv_[c];
  float ga = gamma[c], be = beta[c];
  int r0 = blockIdx.y * RG;
  for (int r = r0; r < r0 + RG; ++r) {
    float v = src[(size_t)r * HD + c];
    float o = fmaxf(ga * (v - mu) * inv + be, 0.0f);
    ushort h, l; split2(o, &h, &l);
    Hh[(size_t)r * HD + c] = h;
    Hl[(size_t)r * HD + c] = l;
  }
}

// ---------------- loss finalize ----------------
__global__ void finalize_loss_k(const float* __restrict__ loss, float* __restrict__ out) {
  if (threadIdx.x == 0) out[BT * 256] = loss[0] * (0.01f * 36.0f / 12288.0f);
}

extern "C" void kernel_launch(void* const* d_in, const int* in_sizes, int n_in,
                              void* d_out, int out_size, void* d_ws, size_t ws_size,
                              hipStream_t stream) {
  const float* x     = (const float*)d_in[0];
  const float* in_W  = (const float*)d_in[1];
  const float* in_b  = (const float*)d_in[2];
  const float* in_g  = (const float*)d_in[3];
  const float* in_be = (const float*)d_in[4];
  const float* sp_W  = (const float*)d_in[5];
  const float* sp_b  = (const float*)d_in[6];
  const float* sp_g  = (const float*)d_in[7];
  const float* sp_be = (const float*)d_in[8];
  const float* sp_gate = (const float*)d_in[9];
  const float* sp_w1 = (const float*)d_in[10];
  const float* dn_W  = (const float*)d_in[11];
  const float* dn_b  = (const float*)d_in[12];
  const float* dn_g  = (const float*)d_in[13];
  const float* dn_be = (const float*)d_in[14];
  const float* out_W = (const float*)d_in[15];
  const float* out_b = (const float*)d_in[16];
  float* out = (float*)d_out;

  // ---- workspace layout ----
  char* base = (char*)d_ws;
  size_t off = 0;
  auto alloc = [&](size_t bytes) { void* p = base + off; off = (off + bytes + 255) & ~(size_t)255; return p; };
  float*  xl     = (float*)alloc((size_t)BT * HD * 4);          // 8 MB
  float*  P      = (float*)alloc((size_t)4 * BT * HD * 4);      // 32 MB; eo = P[0:16MB], y = P+4M floats
  float*  eo     = P;                                           // 4096 x 1024 f32 (alias)
  float*  y      = P + (size_t)4 * 1024 * 1024;                 // 2048 x 1024 f32 (alias)
  float*  psum   = (float*)alloc(NG * HD * 4);
  float*  psumsq = (float*)alloc(NG * HD * 4);
  float*  muv    = (float*)alloc(HD * 4);
  float*  invv   = (float*)alloc(HD * 4);
  float*  g1o    = (float*)alloc(BT * 4);
  float*  g2o    = (float*)alloc(BT * 4);
  float*  loss   = (float*)alloc(256);
  int*    cnt    = (int*)alloc(256);
  int*    toklist= (int*)alloc(NEXP * MAXR * 4);
  ushort* Hh     = (ushort*)alloc((size_t)BT * HD * 2);
  ushort* Hl     = (ushort*)alloc((size_t)BT * HD * 2);
  ushort* XLh    = (ushort*)alloc((size_t)BT * HD * 2);
  ushort* XLl    = (ushort*)alloc((size_t)BT * HD * 2);
  ushort* inWTh  = (ushort*)alloc((size_t)2048 * HD * 2);
  ushort* inWTl  = (ushort*)alloc((size_t)2048 * HD * 2);
  ushort* spWTh  = (ushort*)alloc((size_t)4 * HD * HD * 2);
  ushort* spWTl  = (ushort*)alloc((size_t)4 * HD * HD * 2);
  ushort* dnWTh  = (ushort*)alloc((size_t)4 * HD * HD * 2);
  ushort* dnWTl  = (ushort*)alloc((size_t)4 * HD * HD * 2);
  ushort* outWTh = (ushort*)alloc((size_t)HD * 256 * 2);
  ushort* outWTl = (ushort*)alloc((size_t)HD * 256 * 2);
  // w1 transpose region; Xh/Xl for input x alias its head (dead after input GEMM,
  // and transpose of w1 is launched after the input GEMM in stream order).
  ushort* w1Th   = (ushort*)alloc((size_t)24 * HD * HD * 2);    // 48 MB
  ushort* w1Tl   = (ushort*)alloc((size_t)24 * HD * HD * 2);    // 48 MB
  ushort* Xh     = w1Th;                                        // 2048x2048 bf16 (8 MB)
  ushort* Xl     = w1Th + (size_t)BT * 2048;                    // next 8 MB

  unsigned lk0[4], lk1[4];
  for (int i = 0; i < 4; ++i) tf2x32(0u, 42u, 0u, (unsigned)i, &lk0[i], &lk1[i]);

  dim3 blk(256);
  dim3 gblk(512);
  init_ws_k<<<1, 64, 0, stream>>>(cnt, loss);

  // ---- weight prep (w1 deferred until after input GEMM) ----
  transpose_split_k<<<dim3(32, 64, 1), blk, 0, stream>>>(in_W, inWTh, inWTl, 2048, HD);
  transpose_split_k<<<dim3(32, 32, 4), blk, 0, stream>>>(sp_W, spWTh, spWTl, HD, HD);
  transpose_split_k<<<dim3(32, 32, 4), blk, 0, stream>>>(dn_W, dnWTh, dnWTl, HD, HD);
  transpose_split_k<<<dim3(8, 32, 1), blk, 0, stream>>>(out_W, outWTh, outWTl, HD, 256);
  split_plain_k<<<(BT * 2048) / 1024, blk, 0, stream>>>(x, Xh, Xl);

  // ---- input layer: split-K=4 GEMM, fused reduce+bias+colsum, BN ----
  gemm_mfma_k<0><<<dim3(8, 16, 4), gblk, 0, stream>>>(Xh, Xl, inWTh, inWTl, P,
                                                      nullptr, nullptr, HD, 2048, 16);
  reduce_dense_k<4><<<dim3(4, NG), blk, 0, stream>>>(P, in_b, xl, psum);
  // w1 transpose now (Xh/Xl dead)
  transpose_split_k<<<dim3(32, 32, 24), blk, 0, stream>>>(sp_w1, w1Th, w1Tl, HD, HD);
  fold_mu_k<<<4, blk, 0, stream>>>(psum, muv);
  var_partial_k<<<dim3(4, NG), blk, 0, stream>>>(xl, muv, psumsq);
  fold_inv_k<<<4, blk, 0, stream>>>(psumsq, invv);
  bn_split_k<<<dim3(4, NG), blk, 0, stream>>>(xl, muv, invv, in_g, in_be, Hh, Hl);

  // ---- sparse MoE layers ----
  for (int i = 0; i < 4; ++i) {
    gemm_mfma_k<0><<<dim3(8, 16, 4), gblk, 0, stream>>>(Hh, Hl, spWTh + (size_t)i * HD * HD,
                                                        spWTl + (size_t)i * HD * HD, P,
                                                        nullptr, nullptr, HD, HD, 8);
    reduce_split_k<4><<<dim3(4, NG), blk, 0, stream>>>(P, sp_b + i * HD, xl, XLh, XLl);
    gating_k<<<BT / GT, blk, 0, stream>>>(xl, sp_gate + (size_t)i * HD * NEXP,
                                          cnt + i * 8, toklist, g1o, g2o, loss, lk0[i], lk1[i]);
    gemm_mfma_k<2><<<dim3(8, 32, NEXP), gblk, 0, stream>>>(XLh, XLl,
                                                           w1Th + (size_t)i * NEXP * HD * HD,
                                                           w1Tl + (size_t)i * NEXP * HD * HD,
                                                           eo, cnt + i * 8, toklist, HD, HD, 32);
    combine_sum_k<<<dim3(4, NG), blk, 0, stream>>>(xl, eo, g1o, g2o, y, psum);
    fold_mu_k<<<4, blk, 0, stream>>>(psum, muv);
    var_partial_k<<<dim3(4, NG), blk, 0, stream>>>(y, muv, psumsq);
    fold_inv_k<<<4, blk, 0, stream>>>(psumsq, invv);
    bn_split_k<<<dim3(4, NG), blk, 0, stream>>>(y, muv, invv, sp_g + i * HD,
                                                sp_be + i * HD, Hh, Hl);
  }

  // ---- dense layers ----
  for (int i = 0; i < 4; ++i) {
    gemm_mfma_k<0><<<dim3(8, 16, 4), gblk, 0, stream>>>(Hh, Hl, dnWTh + (size_t)i * HD * HD,
                                                        dnWTl + (size_t)i * HD * HD, P,
                                                        nullptr, nullptr, HD, HD, 8);
    reduce_dense_k<4><<<dim3(4, NG), blk, 0, stream>>>(P, dn_b + i * HD, xl, psum);
    fold_mu_k<<<4, blk, 0, stream>>>(psum, muv);
    var_partial_k<<<dim3(4, NG), blk, 0, stream>>>(xl, muv, psumsq);
    fold_inv_k<<<4, blk, 0, stream>>>(psumsq, invv);
    bn_split_k<<<dim3(4, NG), blk, 0, stream>>>(xl, muv, invv, dn_g + i * HD,
                                                dn_be + i * HD, Hh, Hl);
  }

  // ---- output projection: split-K=8 ----
  gemm_mfma_k<0><<<dim3(2, 16, 8), gblk, 0, stream>>>(Hh, Hl, outWTh, outWTl, P,
                                                      nullptr, nullptr, 256, HD, 4);
  reduce_out_k<<<dim3(1, NG), blk, 0, stream>>>(P, out_b, out);
  finalize_loss_k<<<1, 64, 0, stream>>>(loss, out);
}

// Round 14
// 1040.108 us; speedup vs baseline: 1.0879x; 1.0721x over previous
//
#include <hip/hip_runtime.h>

typedef unsigned int uint;
typedef unsigned short ushort;
typedef short bf16x8 __attribute__((ext_vector_type(8)));
typedef ushort ushort4v __attribute__((ext_vector_type(4)));
typedef float f32x4 __attribute__((ext_vector_type(4)));

#define HD 1024
#define BT 2048
#define NEXP 6
#define MAXR 4096
#define GT 16   // tokens per gating block
#define NG 128  // BN partial-sum groups
#define RG 16   // rows per group (NG*RG == BT)

typedef __attribute__((address_space(1))) void as1_void;
typedef __attribute__((address_space(3))) void as3_void;
#define ASYNC16(g, l) \
  __builtin_amdgcn_global_load_lds((as1_void*)(const void*)(g), (as3_void*)(void*)(l), 16, 0, 0)

// ---------------- bf16 split helpers ----------------
__device__ static inline ushort f32_to_bf16(float f) {
  uint u = __float_as_uint(f);
  u = (u + 0x7fffu + ((u >> 16) & 1u)) >> 16;
  return (ushort)u;
}
__device__ static inline float bf16_to_f32(ushort h) {
  return __uint_as_float(((uint)h) << 16);
}
__device__ static inline void split2(float f, ushort* hi, ushort* lo) {
  ushort h = f32_to_bf16(f);
  *hi = h;
  *lo = f32_to_bf16(f - bf16_to_f32(h));
}

// ---------------- Threefry-2x32 (matches JAX) ----------------
__host__ __device__ static inline unsigned rotl32(unsigned v, int n) {
  return (v << n) | (v >> (32 - n));
}
__host__ __device__ static inline void tf2x32(unsigned k0, unsigned k1,
                                              unsigned x0, unsigned x1,
                                              unsigned* o0, unsigned* o1) {
  unsigned ks0 = k0, ks1 = k1, ks2 = k0 ^ k1 ^ 0x1BD11BDAu;
  x0 += ks0; x1 += ks1;
  const int ra[4] = {13, 15, 26, 6};
  const int rb[4] = {17, 29, 16, 24};
  #pragma unroll
  for (int r = 0; r < 4; ++r) { x0 += x1; x1 = rotl32(x1, ra[r]); x1 ^= x0; }
  x0 += ks1; x1 += ks2 + 1u;
  #pragma unroll
  for (int r = 0; r < 4; ++r) { x0 += x1; x1 = rotl32(x1, rb[r]); x1 ^= x0; }
  x0 += ks2; x1 += ks0 + 2u;
  #pragma unroll
  for (int r = 0; r < 4; ++r) { x0 += x1; x1 = rotl32(x1, ra[r]); x1 ^= x0; }
  x0 += ks0; x1 += ks1 + 3u;
  #pragma unroll
  for (int r = 0; r < 4; ++r) { x0 += x1; x1 = rotl32(x1, rb[r]); x1 ^= x0; }
  x0 += ks1; x1 += ks2 + 4u;
  #pragma unroll
  for (int r = 0; r < 4; ++r) { x0 += x1; x1 = rotl32(x1, ra[r]); x1 ^= x0; }
  x0 += ks2; x1 += ks0 + 5u;
  *o0 = x0; *o1 = x1;
}

// ---------------- init ----------------
__global__ void init_ws_k(int* cnt, float* loss) {
  int t = threadIdx.x;
  if (t < 32) cnt[t] = 0;
  if (t == 32) loss[0] = 0.0f;
}

// ---------------- weight transpose + split: W(K x N) -> Th,Tl (N x K bf16) ----------------
__global__ __launch_bounds__(256) void transpose_split_k(
    const float* __restrict__ W, ushort* __restrict__ Th, ushort* __restrict__ Tl,
    int K, int N) {
  size_t boff = (size_t)blockIdx.z * K * N;
  W += boff; Th += boff; Tl += boff;
  __shared__ float T[32][33];
  int n0 = blockIdx.x * 32, k0 = blockIdx.y * 32;
  int tid = threadIdx.x;
  int r = tid >> 3, c4 = (tid & 7) * 4;
  float4 v = *(const float4*)&W[(size_t)(k0 + r) * N + n0 + c4];
  T[c4 + 0][r] = v.x; T[c4 + 1][r] = v.y; T[c4 + 2][r] = v.z; T[c4 + 3][r] = v.w;
  __syncthreads();
  ushort4v hh, ll;
  #pragma unroll
  for (int j = 0; j < 4; ++j) {
    float f = T[r][c4 + j];
    ushort h, l; split2(f, &h, &l);
    hh[j] = h; ll[j] = l;
  }
  size_t o = (size_t)(n0 + r) * K + k0 + c4;
  *(ushort4v*)&Th[o] = hh;
  *(ushort4v*)&Tl[o] = ll;
}

// ---------------- elementwise split (for input x) ----------------
__global__ __launch_bounds__(256) void split_plain_k(
    const float* __restrict__ X, ushort* __restrict__ Xh, ushort* __restrict__ Xl) {
  size_t i = ((size_t)blockIdx.x * 256 + threadIdx.x) * 4;
  float4 v = *(const float4*)&X[i];
  ushort4v hh, ll;
  float f[4] = {v.x, v.y, v.z, v.w};
  #pragma unroll
  for (int j = 0; j < 4; ++j) { ushort h, l; split2(f[j], &h, &l); hh[j] = h; ll[j] = l; }
  *(ushort4v*)&Xh[i] = hh;
  *(ushort4v*)&Xl[i] = ll;
}

// ---------------- MFMA GEMM, async-staged, swizzled LDS, split-K ----------------
// R9 structure (best measured total): 128x64 tile, 512 threads / 8 waves (each
// wave a 32x32 sub-tile, acc[2][2]), 48 KB double-buffered LDS => 3 blocks/CU.
// NO XCD swizzle: R13 proved the swizzle cuts HBM bytes (53->25 MB) but RAISES
// time (58->93 us) — the GEMM is latency-bound and cross-XCD concurrent reads
// of the same panel act as an L3 latency cache (1 miss feeds 7 cheap hits).
// Double-buffered, prefetch-first, one __syncthreads per k-step.
// MODE 0: C_partial[z] = A @ B^T slice-of-K (no bias, raw f32 partial)
// MODE 2: expert: gather A rows via list, full K, relu, scatter C rows; z = expert
template <int MODE>
__global__ __launch_bounds__(512, 6) void gemm_mfma_k(
    const ushort* __restrict__ Ah, const ushort* __restrict__ Al,
    const ushort* __restrict__ Bh, const ushort* __restrict__ Bl,
    float* __restrict__ P,
    const int* __restrict__ cnt, const int* __restrict__ list,
    int N, int K, int ksteps) {
  int bz = blockIdx.z;
  int row0 = blockIdx.y * 128, col0 = blockIdx.x * 64;
  int nrows = 0, kbase = 0;
  if (MODE == 2) {
    size_t wo = (size_t)bz * N * K;
    Bh += wo; Bl += wo;
    nrows = cnt[bz];
    list += bz * MAXR;
    if (row0 >= nrows) return;
  } else {
    P += (size_t)bz * BT * N;
    kbase = bz * ksteps * 32;
  }
  __shared__ ushort sAh[2][4096], sAl[2][4096], sBh[2][2048], sBl[2][2048];
  int tid = threadIdx.x;
  int lane = tid & 63, w = tid >> 6;
  // wave -> 32x32 output sub-tile: 4 row groups x 2 col groups
  int wm = (w & 3) * 32;
  int wn = (w >> 2) * 32;  // w in 0..7 -> wn 0 or 32

  // A staging: one 16B chunk per thread (512 chunks); slot XOR-swizzled by row
  const ushort *pAh, *pAl, *pBh = Bh, *pBl = Bl;
  {
    int r = tid >> 2;
    int cl = (tid & 3) ^ ((r ^ (r >> 2)) & 3);
    int ra = row0 + r;
    if (MODE == 2) ra = (ra < nrows) ? (list[ra] & (BT - 1)) : 0;
    size_t ao = (size_t)ra * K + kbase + cl * 8;
    pAh = Ah + ao; pAl = Al + ao;
  }
  // B staging: 256 chunks, waves 0-3 only
  if (tid < 256) {
    int r = tid >> 2;
    int cl = (tid & 3) ^ ((r ^ (r >> 2)) & 3);
    size_t bo = (size_t)(col0 + r) * K + kbase + cl * 8;
    pBh = Bh + bo; pBl = Bl + bo;
  }
  int lb = w * 512;  // ushort offset, wave-uniform; lane spreads by 16B in HW

  // fragment LDS offsets (swizzled to match staging)
  int fr = lane & 15, cq = lane >> 4;
  int offA[2], offB[2];
  #pragma unroll
  for (int i = 0; i < 2; ++i) {
    int rA = wm + i * 16 + fr;
    offA[i] = rA * 32 + (cq ^ ((rA ^ (rA >> 2)) & 3)) * 8;
    int rB = wn + i * 16 + fr;
    offB[i] = rB * 32 + (cq ^ ((rB ^ (rB >> 2)) & 3)) * 8;
  }

  f32x4 acc[2][2] = {};

#define STAGE(buf, ko)                       \
  do {                                       \
    ASYNC16(pAh + (ko), sAh[buf] + lb);      \
    ASYNC16(pAl + (ko), sAl[buf] + lb);      \
    if (w < 4) {                             \
      ASYNC16(pBh + (ko), sBh[buf] + lb);    \
      ASYNC16(pBl + (ko), sBl[buf] + lb);    \
    }                                        \
  } while (0)

  // prologue: fill buffer 0
  STAGE(0, 0);
  __syncthreads();

  int cur = 0;
  for (int ks = 0; ks < ksteps; ++ks) {
    if (ks + 1 < ksteps) STAGE(cur ^ 1, (ks + 1) * 32);

    bf16x8 ah[2], al[2], bh[2], bl[2];
    #pragma unroll
    for (int i = 0; i < 2; ++i) {
      ah[i] = *(const bf16x8*)&sAh[cur][offA[i]];
      al[i] = *(const bf16x8*)&sAl[cur][offA[i]];
      bh[i] = *(const bf16x8*)&sBh[cur][offB[i]];
      bl[i] = *(const bf16x8*)&sBl[cur][offB[i]];
    }
    __builtin_amdgcn_s_setprio(1);
    #pragma unroll
    for (int mi = 0; mi < 2; ++mi)
      #pragma unroll
      for (int ni = 0; ni < 2; ++ni) {
        acc[mi][ni] = __builtin_amdgcn_mfma_f32_16x16x32_bf16(ah[mi], bh[ni], acc[mi][ni], 0, 0, 0);
        acc[mi][ni] = __builtin_amdgcn_mfma_f32_16x16x32_bf16(ah[mi], bl[ni], acc[mi][ni], 0, 0, 0);
        acc[mi][ni] = __builtin_amdgcn_mfma_f32_16x16x32_bf16(al[mi], bh[ni], acc[mi][ni], 0, 0, 0);
      }
    __builtin_amdgcn_s_setprio(0);
    __syncthreads();  // drains this step's prefetch (vmcnt 0) + fences LDS
    cur ^= 1;
  }
#undef STAGE

  // epilogue: C/D layout col = lane&15, row = (lane>>4)*4 + reg
  if (MODE == 2) {
    #pragma unroll
    for (int mi = 0; mi < 2; ++mi) {
      int rb = row0 + wm + mi * 16 + cq * 4;
      #pragma unroll
      for (int r = 0; r < 4; ++r) {
        int row = rb + r;
        if (row < nrows) {
          size_t dro = (size_t)list[row] * N;
          #pragma unroll
          for (int ni = 0; ni < 2; ++ni)
            P[dro + col0 + wn + ni * 16 + fr] = fmaxf(acc[mi][ni][r], 0.0f);
        }
      }
    }
  } else {
    #pragma unroll
    for (int mi = 0; mi < 2; ++mi) {
      int rb = row0 + wm + mi * 16 + cq * 4;
      #pragma unroll
      for (int r = 0; r < 4; ++r) {
        size_t ro = (size_t)(rb + r) * N;
        #pragma unroll
        for (int ni = 0; ni < 2; ++ni)
          P[ro + col0 + wn + ni * 16 + fr] = acc[mi][ni][r];
      }
    }
  }
}

// ---------------- split-K reduce + bias -> xl f32, + BN column partial sums ----------------
template <int NS>
__global__ __launch_bounds__(256) void reduce_dense_k(
    const float* __restrict__ P, const float* __restrict__ bias,
    float* __restrict__ xl, float* __restrict__ psum) {
  int c = blockIdx.x * 256 + threadIdx.x;
  int r0 = blockIdx.y * RG;
  float bv = bias[c];
  float s = 0.0f;
  for (int r = r0; r < r0 + RG; ++r) {
    float v = bv;
    #pragma unroll
    for (int j = 0; j < NS; ++j) v += P[(size_t)j * BT * HD + (size_t)r * HD + c];
    xl[(size_t)r * HD + c] = v;
    s += v;
  }
  psum[blockIdx.y * HD + c] = s;
}

// ---------------- split-K reduce + bias -> xl f32 + bf16 hi/lo (MoE input) ----------------
template <int NS>
__global__ __launch_bounds__(256) void reduce_split_k(
    const float* __restrict__ P, const float* __restrict__ bias,
    float* __restrict__ xl, ushort* __restrict__ Xh, ushort* __restrict__ Xl2) {
  int c = blockIdx.x * 256 + threadIdx.x;
  int r0 = blockIdx.y * RG;
  float bv = bias[c];
  for (int r = r0; r < r0 + RG; ++r) {
    float v = bv;
    #pragma unroll
    for (int j = 0; j < NS; ++j) v += P[(size_t)j * BT * HD + (size_t)r * HD + c];
    xl[(size_t)r * HD + c] = v;
    ushort h, l; split2(v, &h, &l);
    Xh[(size_t)r * HD + c] = h;
    Xl2[(size_t)r * HD + c] = l;
  }
}

// ---------------- output reduce: out = sum P + bias ----------------
__global__ __launch_bounds__(256) void reduce_out_k(
    const float* __restrict__ P, const float* __restrict__ bias,
    float* __restrict__ out) {
  int c = threadIdx.x;
  int r0 = blockIdx.y * RG;
  float bv = bias[c];
  for (int r = r0; r < r0 + RG; ++r) {
    float v = bv;
    #pragma unroll
    for (int j = 0; j < 8; ++j) v += P[(size_t)j * BT * 256 + (size_t)r * 256 + c];
    out[(size_t)r * 256 + c] = v;
  }
}

// ---------------- gating: 16 tokens per 256-thread block ----------------
__global__ __launch_bounds__(256) void gating_k(
    const float* __restrict__ xl, const float* __restrict__ wg,
    int* __restrict__ cnt, int* __restrict__ toklist,
    float* __restrict__ g1o, float* __restrict__ g2o,
    float* __restrict__ loss, unsigned key0, unsigned key1) {
  int tid = threadIdx.x;
  int lane = tid & 63, wv = tid >> 6;
  int q = lane >> 4, ql = lane & 15;
  int t = wv * 4 + q;                 // token slot 0..15 within block
  int b = blockIdx.x * GT + t;        // global token id

  const float* row = xl + (size_t)b * HD;
  float p[NEXP] = {0, 0, 0, 0, 0, 0};
  for (int d = ql; d < HD; d += 16) {
    float xv = row[d];
    const float* w = wg + (size_t)d * NEXP;
    #pragma unroll
    for (int e = 0; e < NEXP; ++e) p[e] += xv * w[e];
  }
  #pragma unroll
  for (int off = 8; off > 0; off >>= 1)
    #pragma unroll
    for (int e = 0; e < NEXP; ++e) p[e] += __shfl_xor(p[e], off);

  __shared__ int   li1[GT], li2[GT];
  __shared__ float lg1[GT], lg2[GT], lgg1[GT];
  __shared__ int   base_s[NEXP];

  if (ql == 0) {
    float mx = p[0];
    #pragma unroll
    for (int e = 1; e < NEXP; ++e) mx = fmaxf(mx, p[e]);
    float ex[NEXP], s = 0.0f;
    #pragma unroll
    for (int e = 0; e < NEXP; ++e) { ex[e] = expf(p[e] - mx); s += ex[e]; }
    float raw[NEXP];
    #pragma unroll
    for (int e = 0; e < NEXP; ++e) raw[e] = ex[e] / s;
    int i1 = 0; float gg1 = raw[0];
    #pragma unroll
    for (int e = 1; e < NEXP; ++e) if (raw[e] > gg1) { gg1 = raw[e]; i1 = e; }
    int i2 = -1; float gg2 = -1.0f;
    #pragma unroll
    for (int e = 0; e < NEXP; ++e) {
      float v = (e == i1) ? 0.0f : raw[e];
      if (v > gg2) { gg2 = v; i2 = e; }
    }
    float den = gg1 + gg2 + 1e-9f;
    float g1n = gg1 / den;
    float g2n = gg2 / den;
    unsigned o0, o1;
    tf2x32(key0, key1, 0u, (unsigned)b, &o0, &o1);
    unsigned bits = o0 ^ o1;
    float prob = __uint_as_float((bits >> 9) | 0x3f800000u) - 1.0f;
    int keep = prob < (g2n / 0.2f);
    li1[t] = i1;
    li2[t] = keep ? i2 : -1;
    lg1[t] = g1n;
    lg2[t] = keep ? g2n : 0.0f;
    lgg1[t] = gg1;
  }
  __syncthreads();

  if (tid < NEXP) {
    int c = 0;
    for (int j = 0; j < GT; ++j) c += (li1[j] == tid) + (li2[j] == tid);
    base_s[tid] = (c > 0) ? atomicAdd(&cnt[tid], c) : 0;
  }
  if (tid == 64) {  // loss partial: one atomic per block
    float s = 0.0f;
    for (int j = 0; j < GT; ++j) s += lgg1[j];
    atomicAdd(loss, s);
  }
  __syncthreads();

  if (tid < GT) {
    int tt = tid;
    int i1 = li1[tt], i2 = li2[tt];
    int bb = blockIdx.x * GT + tt;
    g1o[bb] = lg1[tt];
    g2o[bb] = lg2[tt];
    int o1 = 0, o2 = 0;
    for (int j = 0; j < tt; ++j) {
      o1 += (li1[j] == i1) + (li2[j] == i1);
      o2 += (li1[j] == i2) + (li2[j] == i2);
    }
    toklist[i1 * MAXR + base_s[i1] + o1] = bb;
    if (i2 >= 0) toklist[i2 * MAXR + base_s[i2] + o2] = BT + bb;
  }
}

// ---------------- combine + column partial sums ----------------
__global__ __launch_bounds__(256) void combine_sum_k(
    const float* __restrict__ xl, const float* __restrict__ eo,
    const float* __restrict__ g1o, const float* __restrict__ g2o,
    float* __restrict__ y, float* __restrict__ psum) {
  int c = blockIdx.x * 256 + threadIdx.x;
  int r0 = blockIdx.y * RG;
  float s = 0.0f;
  for (int r = r0; r < r0 + RG; ++r) {
    float v = xl[(size_t)r * HD + c];
    float w1g = g1o[r];
    v += w1g * eo[(size_t)r * HD + c];
    float w2g = g2o[r];
    if (w2g != 0.0f) v += w2g * eo[(size_t)(r + BT) * HD + c];
    y[(size_t)r * HD + c] = v;
    s += v;
  }
  psum[blockIdx.y * HD + c] = s;
}

// ---------------- fold psum -> mu (tiny) ----------------
__global__ __launch_bounds__(256) void fold_mu_k(
    const float* __restrict__ psum, float* __restrict__ mu) {
  int c = blockIdx.x * 256 + threadIdx.x;
  float s = 0.0f;
  for (int i = 0; i < NG; ++i) s += psum[i * HD + c];
  mu[c] = s * (1.0f / 2048.0f);
}

// ---------------- fold psumsq -> inv (tiny) ----------------
__global__ __launch_bounds__(256) void fold_inv_k(
    const float* __restrict__ psumsq, float* __restrict__ inv) {
  int c = blockIdx.x * 256 + threadIdx.x;
  float ss = 0.0f;
  for (int i = 0; i < NG; ++i) ss += psumsq[i * HD + c];
  float var = ss * (1.0f / 2048.0f);
  inv[c] = 1.0f / sqrtf(var + 1e-5f);
}

__global__ __launch_bounds__(256) void var_partial_k(
    const float* __restrict__ src, const float* __restrict__ mu_,
    float* __restrict__ psumsq) {
  int c = blockIdx.x * 256 + threadIdx.x;
  float mu = mu_[c];
  int r0 = blockIdx.y * RG;
  float ss = 0.0f;
  for (int r = r0; r < r0 + RG; ++r) {
    float d = src[(size_t)r * HD + c] - mu;
    ss += d * d;
  }
  psumsq[blockIdx.y * HD + c] = ss;
}

// ---------------- BN apply + relu -> bf16 hi/lo split ----------------
__global__ __launch_bounds__(256) void bn_split_k(
    const float* __restrict__ src, const float* __restrict__ mu_,
    const float* __restrict__ inv_, const float* __restrict__ gamma,
    const float* __restrict__ beta, ushort* __restrict__ Hh,
    ushort* __restrict__ Hl) {
  int c = blockIdx.x * 256 + threadIdx.x;
  float mu = mu_[c];
  float inv = inv_[c];
  float ga = gamma[c], be = beta[c];
  int r0 = blockIdx.y * RG;
  for (int r = r0; r < r0 + RG; ++r) {
    float v = src[(size_t)r * HD + c];
    float o = fmaxf(ga * (v - mu) * inv + be, 0.0f);
    ushort h, l; split2(o, &h, &l);
    Hh[(size_t)r * HD + c] = h;
    Hl[(size_t)r * HD + c] = l;
  }
}

// ---------------- loss finalize ----------------
__global__ void finalize_loss_k(const float* __restrict__ loss, float* __restrict__ out) {
  if (threadIdx.x == 0) out[BT * 256] = loss[0] * (0.01f * 36.0f / 12288.0f);
}

extern "C" void kernel_launch(void* const* d_in, const int* in_sizes, int n_in,
                              void* d_out, int out_size, void* d_ws, size_t ws_size,
                              hipStream_t stream) {
  const float* x     = (const float*)d_in[0];
  const float* in_W  = (const float*)d_in[1];
  const float* in_b  = (const float*)d_in[2];
  const float* in_g  = (const float*)d_in[3];
  const float* in_be = (const float*)d_in[4];
  const float* sp_W  = (const float*)d_in[5];
  const float* sp_b  = (const float*)d_in[6];
  const float* sp_g  = (const float*)d_in[7];
  const float* sp_be = (const float*)d_in[8];
  const float* sp_gate = (const float*)d_in[9];
  const float* sp_w1 = (const float*)d_in[10];
  const float* dn_W  = (const float*)d_in[11];
  const float* dn_b  = (const float*)d_in[12];
  const float* dn_g  = (const float*)d_in[13];
  const float* dn_be = (const float*)d_in[14];
  const float* out_W = (const float*)d_in[15];
  const float* out_b = (const float*)d_in[16];
  float* out = (float*)d_out;

  // ---- workspace layout ----
  char* base = (char*)d_ws;
  size_t off = 0;
  auto alloc = [&](size_t bytes) { void* p = base + off; off = (off + bytes + 255) & ~(size_t)255; return p; };
  float*  xl     = (float*)alloc((size_t)BT * HD * 4);          // 8 MB
  float*  P      = (float*)alloc((size_t)4 * BT * HD * 4);      // 32 MB; eo = P[0:16MB], y = P+4M floats
  float*  eo     = P;                                           // 4096 x 1024 f32 (alias)
  float*  y      = P + (size_t)4 * 1024 * 1024;                 // 2048 x 1024 f32 (alias)
  float*  psum   = (float*)alloc(NG * HD * 4);
  float*  psumsq = (float*)alloc(NG * HD * 4);
  float*  muv    = (float*)alloc(HD * 4);
  float*  invv   = (float*)alloc(HD * 4);
  float*  g1o    = (float*)alloc(BT * 4);
  float*  g2o    = (float*)alloc(BT * 4);
  float*  loss   = (float*)alloc(256);
  int*    cnt    = (int*)alloc(256);
  int*    toklist= (int*)alloc(NEXP * MAXR * 4);
  ushort* Hh     = (ushort*)alloc((size_t)BT * HD * 2);
  ushort* Hl     = (ushort*)alloc((size_t)BT * HD * 2);
  ushort* XLh    = (ushort*)alloc((size_t)BT * HD * 2);
  ushort* XLl    = (ushort*)alloc((size_t)BT * HD * 2);
  ushort* inWTh  = (ushort*)alloc((size_t)2048 * HD * 2);
  ushort* inWTl  = (ushort*)alloc((size_t)2048 * HD * 2);
  ushort* spWTh  = (ushort*)alloc((size_t)4 * HD * HD * 2);
  ushort* spWTl  = (ushort*)alloc((size_t)4 * HD * HD * 2);
  ushort* dnWTh  = (ushort*)alloc((size_t)4 * HD * HD * 2);
  ushort* dnWTl  = (ushort*)alloc((size_t)4 * HD * HD * 2);
  ushort* outWTh = (ushort*)alloc((size_t)HD * 256 * 2);
  ushort* outWTl = (ushort*)alloc((size_t)HD * 256 * 2);
  // w1 transpose region; Xh/Xl for input x alias its head (dead after input GEMM,
  // and transpose of w1 is launched after the input GEMM in stream order).
  ushort* w1Th   = (ushort*)alloc((size_t)24 * HD * HD * 2);    // 48 MB
  ushort* w1Tl   = (ushort*)alloc((size_t)24 * HD * HD * 2);    // 48 MB
  ushort* Xh     = w1Th;                                        // 2048x2048 bf16 (8 MB)
  ushort* Xl     = w1Th + (size_t)BT * 2048;                    // next 8 MB

  unsigned lk0[4], lk1[4];
  for (int i = 0; i < 4; ++i) tf2x32(0u, 42u, 0u, (unsigned)i, &lk0[i], &lk1[i]);

  dim3 blk(256);
  dim3 gblk(512);
  init_ws_k<<<1, 64, 0, stream>>>(cnt, loss);

  // ---- weight prep (w1 deferred until after input GEMM) ----
  transpose_split_k<<<dim3(32, 64, 1), blk, 0, stream>>>(in_W, inWTh, inWTl, 2048, HD);
  transpose_split_k<<<dim3(32, 32, 4), blk, 0, stream>>>(sp_W, spWTh, spWTl, HD, HD);
  transpose_split_k<<<dim3(32, 32, 4), blk, 0, stream>>>(dn_W, dnWTh, dnWTl, HD, HD);
  transpose_split_k<<<dim3(8, 32, 1), blk, 0, stream>>>(out_W, outWTh, outWTl, HD, 256);
  split_plain_k<<<(BT * 2048) / 1024, blk, 0, stream>>>(x, Xh, Xl);

  // ---- input layer: split-K=2 GEMM (512 blocks = one residency round), reduce, BN ----
  gemm_mfma_k<0><<<dim3(16, 16, 2), gblk, 0, stream>>>(Xh, Xl, inWTh, inWTl, P,
                                                       nullptr, nullptr, HD, 2048, 32);
  reduce_dense_k<2><<<dim3(4, NG), blk, 0, stream>>>(P, in_b, xl, psum);
  // w1 transpose now (Xh/Xl dead)
  transpose_split_k<<<dim3(32, 32, 24), blk, 0, stream>>>(sp_w1, w1Th, w1Tl, HD, HD);
  fold_mu_k<<<4, blk, 0, stream>>>(psum, muv);
  var_partial_k<<<dim3(4, NG), blk, 0, stream>>>(xl, muv, psumsq);
  fold_inv_k<<<4, blk, 0, stream>>>(psumsq, invv);
  bn_split_k<<<dim3(4, NG), blk, 0, stream>>>(xl, muv, invv, in_g, in_be, Hh, Hl);

  // ---- sparse MoE layers ----
  for (int i = 0; i < 4; ++i) {
    gemm_mfma_k<0><<<dim3(16, 16, 2), gblk, 0, stream>>>(Hh, Hl, spWTh + (size_t)i * HD * HD,
                                                         spWTl + (size_t)i * HD * HD, P,
                                                         nullptr, nullptr, HD, HD, 16);
    reduce_split_k<2><<<dim3(4, NG), blk, 0, stream>>>(P, sp_b + i * HD, xl, XLh, XLl);
    gating_k<<<BT / GT, blk, 0, stream>>>(xl, sp_gate + (size_t)i * HD * NEXP,
                                          cnt + i * 8, toklist, g1o, g2o, loss, lk0[i], lk1[i]);
    gemm_mfma_k<2><<<dim3(16, 32, NEXP), gblk, 0, stream>>>(XLh, XLl,
                                                            w1Th + (size_t)i * NEXP * HD * HD,
                                                            w1Tl + (size_t)i * NEXP * HD * HD,
                                                            eo, cnt + i * 8, toklist, HD, HD, 32);
    combine_sum_k<<<dim3(4, NG), blk, 0, stream>>>(xl, eo, g1o, g2o, y, psum);
    fold_mu_k<<<4, blk, 0, stream>>>(psum, muv);
    var_partial_k<<<dim3(4, NG), blk, 0, stream>>>(y, muv, psumsq);
    fold_inv_k<<<4, blk, 0, stream>>>(psumsq, invv);
    bn_split_k<<<dim3(4, NG), blk, 0, stream>>>(y, muv, invv, sp_g + i * HD,
                                                sp_be + i * HD, Hh, Hl);
  }

  // ---- dense layers ----
  for (int i = 0; i < 4; ++i) {
    gemm_mfma_k<0><<<dim3(16, 16, 2), gblk, 0, stream>>>(Hh, Hl, dnWTh + (size_t)i * HD * HD,
                                                         dnWTl + (size_t)i * HD * HD, P,
                                                         nullptr, nullptr, HD, HD, 16);
    reduce_dense_k<2><<<dim3(4, NG), blk, 0, stream>>>(P, dn_b + i * HD, xl, psum);
    fold_mu_k<<<4, blk, 0, stream>>>(psum, muv);
    var_partial_k<<<dim3(4, NG), blk, 0, stream>>>(xl, muv, psumsq);
    fold_inv_k<<<4, blk, 0, stream>>>(psumsq, invv);
    bn_split_k<<<dim3(4, NG), blk, 0, stream>>>(xl, muv, invv, dn_g + i * HD,
                                                dn_be + i * HD, Hh, Hl);
  }

  // ---- output projection: split-K=8 ----
  gemm_mfma_k<0><<<dim3(4, 16, 8), gblk, 0, stream>>>(Hh, Hl, outWTh, outWTl, P,
                                                      nullptr, nullptr, 256, HD, 4);
  reduce_out_k<<<dim3(1, NG), blk, 0, stream>>>(P, out_b, out);
  finalize_loss_k<<<1, 64, 0, stream>>>(loss, out);
}